// Round 1
// baseline (92.351 us; speedup 1.0000x reference)
//
#include <hip/hip_runtime.h>
#include <cstdint>
#include <cstddef>

// MemristorDense R12: table-precompute restructure.
// y[b,o] = sum_i 0.5*(|w|+delta)*(2x)^E  (pos - neg),  delta = maxw*GMIN/GSPAN,
// using C*kG == 0.5 exactly. k_tab precomputes EW[i][o] = (Ep,En,Wp',Wn') with
// W' = log2(0.5*(|w|+delta)); k_main's hot step is 1 float4 load -> fma -> exp2.
// 2-deep prefetch on the lane-varying EW stream; bias folded to biasv[o] table.

#define B128 128
#define NIN  1024
#define NI   1025
#define NO   512
#define NJ   1024
#define GMIN 1.0e-5f
#define GSPAN (1.0e-3f - 1.0e-5f)
#define ZCH  8      // K-chunks over [0,1024)
#define CHUNK 128

__device__ __forceinline__ float flog2(float x) { return __builtin_amdgcn_logf(x); }
__device__ __forceinline__ float fexp2(float x) { return __builtin_amdgcn_exp2f(x); }

// Kernel 1 (grid 256 x 1024): zero out, LT[i][b]=1+log2(x[b][i]), block max -> bmax[256].
__global__ __launch_bounds__(1024) void k_prep(
    const float* __restrict__ x,
    const float* __restrict__ wp, const float* __restrict__ wn,
    const float* __restrict__ bp, const float* __restrict__ bn,
    float* __restrict__ LT, float* __restrict__ bmax, float* __restrict__ out)
{
    const int tid = blockIdx.x * 1024 + threadIdx.x;   // [0, 262144)

    if (tid < B128 * NO) out[tid] = 0.0f;

    if (tid < NI * B128) {
        int i = tid >> 7, b = tid & 127;
        float xv = (i < NIN) ? x[b * NIN + i] : 1.0f;
        LT[tid] = 1.0f + flog2(xv);                 // log2(2x); x=0 -> -inf (correct)
    }

    // NIN*NO = 524288 = 2 * 262144 exactly
    float m = fmaxf(fmaxf(__builtin_fabsf(wp[tid]), __builtin_fabsf(wn[tid])),
                    fmaxf(__builtin_fabsf(wp[tid + 262144]), __builtin_fabsf(wn[tid + 262144])));
    if (tid < NO) m = fmaxf(m, fmaxf(__builtin_fabsf(bp[tid]), __builtin_fabsf(bn[tid])));

    __shared__ float red[16];
    #pragma unroll
    for (int off = 32; off > 0; off >>= 1) m = fmaxf(m, __shfl_down(m, off, 64));
    if ((threadIdx.x & 63) == 0) red[threadIdx.x >> 6] = m;
    __syncthreads();
    if (threadIdx.x < 16) {
        m = red[threadIdx.x];
        #pragma unroll
        for (int off = 8; off > 0; off >>= 1) m = fmaxf(m, __shfl_down(m, off, 16));
        if (threadIdx.x == 0) bmax[blockIdx.x] = m;
    }
}

// Kernel 2 (grid 1025 x 512): per row i, EW[i][o] = (Ep,En,Wp',Wn') for i<1024;
// row 1024 -> biasv[o] = 0.5(|bp|+delta)*n_p - 0.5(|bn|+delta)*n_n (L=1 -> 2^E = n).
__global__ __launch_bounds__(512) void k_tab(
    const float* __restrict__ nd,
    const float* __restrict__ wp, const float* __restrict__ wn,
    const float* __restrict__ bp, const float* __restrict__ bn,
    const float* __restrict__ bmax,
    float4* __restrict__ ew, float* __restrict__ biasv)
{
    const int i = blockIdx.x;
    const int o = threadIdx.x;
    const int lane = threadIdx.x & 63;

    // reduce 256 per-block maxima (redundant per wave; L2-hot)
    float m = fmaxf(fmaxf(bmax[lane], bmax[lane + 64]),
                    fmaxf(bmax[lane + 128], bmax[lane + 192]));
    #pragma unroll
    for (int off = 32; off > 0; off >>= 1) m = fmaxf(m, __shfl_down(m, off, 64));
    const float maxw = __shfl(m, 0, 64);
    const float hdelta = 0.5f * (maxw * (GMIN / GSPAN));   // 0.5*delta

    const float2 nv = *(const float2*)(nd + (size_t)i * NJ + 2 * o);
    if (i < NIN) {
        const float wvp = __builtin_fabsf(wp[(size_t)i * NO + o]);
        const float wvn = __builtin_fabsf(wn[(size_t)i * NO + o]);
        ew[(size_t)i * NO + o] = make_float4(
            flog2(nv.x), flog2(nv.y),
            flog2(__builtin_fmaf(0.5f, wvp, hdelta)),
            flog2(__builtin_fmaf(0.5f, wvn, hdelta)));
    } else {
        const float gp = __builtin_fmaf(0.5f, __builtin_fabsf(bp[o]), hdelta);
        const float gn = __builtin_fmaf(0.5f, __builtin_fabsf(bn[o]), hdelta);
        biasv[o] = nv.x * gp - nv.y * gn;
    }
}

// Kernel 3: grid (8 o-tiles, 8 b-tiles, 8 K-chunks) x 512 threads (8 waves).
// Wave s handles i = z*128 + s + 8k, k in [0,16). Per step: 1 float4 EW load
// (2-deep prefetch) + 4 float4 L loads (uniform, 1-deep) + 32 exp2. LDS reduce
// across 8 waves, bias via biasv (z==0 only), atomicAdd into out (no C scale).
__global__ __launch_bounds__(512) void k_main(
    const float4* __restrict__ ew, const float* __restrict__ LT,
    const float* __restrict__ biasv, float* __restrict__ out)
{
    const int lane = threadIdx.x & 63;
    const int s    = threadIdx.x >> 6;      // wave id [0,8)
    const int o    = (blockIdx.x << 6) + lane;
    const int b0   = blockIdx.y << 4;       // 16 batches per block
    const int i0   = blockIdx.z * CHUNK + s;

    const float4* pEW = ew + (size_t)i0 * NO + o;
    const float*  pL  = LT + (size_t)i0 * B128 + b0;

    float accp[16], accn[16];
    #pragma unroll
    for (int k = 0; k < 16; ++k) { accp[k] = 0.0f; accn[k] = 0.0f; }

    // prologue: EW 2-deep, L 1-deep
    float4 e0 = pEW[0];
    float4 e1 = pEW[8 * NO];
    const float4* pE = pEW + 16 * NO;       // points at k=2
    float4 La = *(const float4*)(pL);
    float4 Lb = *(const float4*)(pL + 4);
    float4 Lc = *(const float4*)(pL + 8);
    float4 Ld = *(const float4*)(pL + 12);

#define STEP(E) do { \
        const float Lv[16] = {La.x, La.y, La.z, La.w, Lb.x, Lb.y, Lb.z, Lb.w, \
                              Lc.x, Lc.y, Lc.z, Lc.w, Ld.x, Ld.y, Ld.z, Ld.w}; \
        _Pragma("unroll") \
        for (int j = 0; j < 16; ++j) { \
            accp[j] += fexp2(__builtin_fmaf((E).x, Lv[j], (E).z)); \
            accn[j] += fexp2(__builtin_fmaf((E).y, Lv[j], (E).w)); \
        } \
    } while (0)

    #pragma unroll 2
    for (int k = 0; k < 14; ++k) {
        const float4 e2 = *pE;               // EW for step k+2
        pE += 8 * NO;
        pL += 8 * B128;
        const float4 Lan = *(const float4*)(pL);
        const float4 Lbn = *(const float4*)(pL + 4);
        const float4 Lcn = *(const float4*)(pL + 8);
        const float4 Ldn = *(const float4*)(pL + 12);

        STEP(e0);

        e0 = e1; e1 = e2;
        La = Lan; Lb = Lbn; Lc = Lcn; Ld = Ldn;
    }
    {   // k = 14: prefetch L for k=15 only
        pL += 8 * B128;
        const float4 Lan = *(const float4*)(pL);
        const float4 Lbn = *(const float4*)(pL + 4);
        const float4 Lcn = *(const float4*)(pL + 8);
        const float4 Ldn = *(const float4*)(pL + 12);
        STEP(e0);
        e0 = e1;
        La = Lan; Lb = Lbn; Lc = Lcn; Ld = Ldn;
    }
    STEP(e0);   // k = 15
#undef STEP

    // LDS reduce across the 8 waves. Row stride 33 floats -> conflict-free.
    __shared__ float lds[8 * 64 * 33];   // 67584 B
    {
        const int base = (s * 64 + lane) * 33;
        #pragma unroll
        for (int j = 0; j < 16; ++j) { lds[base + j] = accp[j]; lds[base + 16 + j] = accn[j]; }
    }
    __syncthreads();

    float bias = 0.0f;
    if (blockIdx.z == 0) bias = biasv[o];   // batch-independent, added once per output

    {
        const int l = threadIdx.x & 63;
        #pragma unroll
        for (int r = 0; r < 2; ++r) {
            const int bb = (threadIdx.x >> 6) + (r << 3);   // [0,16)
            float sum = bias;
            #pragma unroll
            for (int w = 0; w < 8; ++w) {
                const int base = (w * 64 + l) * 33;
                sum += lds[base + bb] - lds[base + 16 + bb];
            }
            unsafeAtomicAdd(out + (size_t)(b0 + bb) * NO + (blockIdx.x << 6) + l, sum);
        }
    }
}

extern "C" void kernel_launch(void* const* d_in, const int* in_sizes, int n_in,
                              void* d_out, int out_size, void* d_ws, size_t ws_size,
                              hipStream_t stream)
{
    const float* x  = (const float*)d_in[0];
    const float* wp = (const float*)d_in[1];
    const float* wn = (const float*)d_in[2];
    const float* bp = (const float*)d_in[3];
    const float* bn = (const float*)d_in[4];
    const float* nd = (const float*)d_in[5];
    float* out = (float*)d_out;

    unsigned char* ws = (unsigned char*)d_ws;
    float*  bmax  = (float*)ws;                 // 256 floats
    float*  LT    = (float*)(ws + 4096);        // 1025*128*4 = 524800 B
    float4* EW    = (float4*)(ws + 528896);     // 1024*512*16 = 8388608 B (16B aligned)
    float*  biasv = (float*)(ws + 8917504);     // 512 floats

    k_prep<<<256, 1024, 0, stream>>>(x, wp, wn, bp, bn, LT, bmax, out);
    k_tab<<<NI, 512, 0, stream>>>(nd, wp, wn, bp, bn, bmax, EW, biasv);
    k_main<<<dim3(8, 8, ZCH), 512, 0, stream>>>(EW, LT, biasv, out);
}